// Round 4
// baseline (236.305 us; speedup 1.0000x reference)
//
#include <hip/hip_runtime.h>
#include <hip/hip_fp16.h>

#define T_SEQ 2048
#define D_MODEL 1024
#define NB 2
#define NH 16
#define HD 64

using f16x8 = __attribute__((ext_vector_type(8))) _Float16;
using f16x4 = __attribute__((ext_vector_type(4))) _Float16;
using f32x4 = __attribute__((ext_vector_type(4))) float;

__device__ __forceinline__ void gload_lds16(const void* g, void* l) {
    __builtin_amdgcn_global_load_lds((const __attribute__((address_space(1))) void*)g,
                                     (__attribute__((address_space(3))) void*)l, 16, 0, 0);
}

// ---------- absmax: y<4 -> x slice y (slot 0); y>=4 -> W[y-4] (slot 1+y-4) ----------
__global__ __launch_bounds__(256)
void k_absmax8(const float* __restrict__ x,
               const float* __restrict__ w0, const float* __restrict__ w1,
               const float* __restrict__ w2, const float* __restrict__ w3,
               unsigned int* __restrict__ amax) {
    const int y = blockIdx.y;
    const float* p; int slot;
    if (y < 4) { p = x + (long)y * 1048576; slot = 0; }
    else { int w = y - 4; p = (w == 0) ? w0 : (w == 1) ? w1 : (w == 2) ? w2 : w3; slot = 1 + w; }
    const long n4 = 262144;
    long i = (long)blockIdx.x * blockDim.x + threadIdx.x;
    const long stride = (long)gridDim.x * blockDim.x;
    float m = 0.f;
    for (; i < n4; i += stride) {
        float4 v = ((const float4*)p)[i];
        m = fmaxf(fmaxf(fmaxf(fabsf(v.x), fabsf(v.y)), fmaxf(fabsf(v.z), fabsf(v.w))), m);
    }
    #pragma unroll
    for (int off = 32; off; off >>= 1) m = fmaxf(m, __shfl_xor(m, off));
    if ((threadIdx.x & 63) == 0 && m > 0.f) atomicMax(amax + slot, __float_as_uint(m));
}

// ---------- quantize to integer codes (f16): same y decode as k_absmax8 ----------
__global__ __launch_bounds__(256)
void k_quant8(const float* __restrict__ x,
              const float* __restrict__ w0, const float* __restrict__ w1,
              const float* __restrict__ w2, const float* __restrict__ w3,
              _Float16* __restrict__ xq,
              _Float16* __restrict__ o0, _Float16* __restrict__ o1,
              _Float16* __restrict__ o2, _Float16* __restrict__ o3,
              const unsigned int* __restrict__ amax) {
    const int y = blockIdx.y;
    const float* p; _Float16* o; int slot;
    if (y < 4) { p = x + (long)y * 1048576; o = xq + (long)y * 1048576; slot = 0; }
    else {
        int w = y - 4;
        p = (w == 0) ? w0 : (w == 1) ? w1 : (w == 2) ? w2 : w3;
        o = (w == 0) ? o0 : (w == 1) ? o1 : (w == 2) ? o2 : o3;
        slot = 1 + w;
    }
    float scale = fmaxf(__uint_as_float(amax[slot]) / 127.0f, 1e-8f);
    const long n4 = 262144;
    long i = (long)blockIdx.x * blockDim.x + threadIdx.x;
    const long stride = (long)gridDim.x * blockDim.x;
    for (; i < n4; i += stride) {
        float4 v = ((const float4*)p)[i];
        f16x4 q;
        q[0] = (_Float16)fminf(127.f, fmaxf(-128.f, rintf(v.x / scale)));
        q[1] = (_Float16)fminf(127.f, fmaxf(-128.f, rintf(v.y / scale)));
        q[2] = (_Float16)fminf(127.f, fmaxf(-128.f, rintf(v.z / scale)));
        q[3] = (_Float16)fminf(127.f, fmaxf(-128.f, rintf(v.w / scale)));
        ((f16x4*)o)[i] = q;
    }
}

// plain quant for y buffer
__global__ __launch_bounds__(256)
void k_quant(const float* __restrict__ in, _Float16* __restrict__ out,
             const unsigned int* __restrict__ amax, long n4) {
    float scale = fmaxf(__uint_as_float(*amax) / 127.0f, 1e-8f);
    long i = (long)blockIdx.x * blockDim.x + threadIdx.x;
    const long stride = (long)gridDim.x * blockDim.x;
    for (; i < n4; i += stride) {
        float4 v = ((const float4*)in)[i];
        f16x4 q;
        q[0] = (_Float16)fminf(127.f, fmaxf(-128.f, rintf(v.x / scale)));
        q[1] = (_Float16)fminf(127.f, fmaxf(-128.f, rintf(v.y / scale)));
        q[2] = (_Float16)fminf(127.f, fmaxf(-128.f, rintf(v.z / scale)));
        q[3] = (_Float16)fminf(127.f, fmaxf(-128.f, rintf(v.w / scale)));
        ((f16x4*)out)[i] = q;
    }
}

// ---------- shared GEMM core: 128x128 tile, K=1024, codes @ codes^T ----------
__device__ __forceinline__ void gemm_core(const _Float16* __restrict__ A,
                                          const _Float16* __restrict__ Bw,
                                          int m0, int n0, int tid, f32x4 (&acc)[4][4]) {
    __shared__ _Float16 Asm[128 * 32];
    __shared__ _Float16 Bsm[128 * 32];
    const int lane = tid & 63, wid = tid >> 6;
    const int r16 = lane & 15, g = lane >> 4;
    const int wr = wid >> 1, wc = wid & 1;
    #pragma unroll
    for (int m = 0; m < 4; ++m)
        #pragma unroll
        for (int n = 0; n < 4; ++n) acc[m][n] = (f32x4){0.f, 0.f, 0.f, 0.f};
    for (int kt = 0; kt < 1024; kt += 32) {
        __syncthreads();
        #pragma unroll
        for (int s2 = 0; s2 < 2; ++s2) {
            int c = tid + s2 * 256;
            int row = c >> 2, cb = (c & 3) * 8;
            gload_lds16(&A[(long)(m0 + row) * 1024 + kt + cb], &Asm[c * 8]);
            gload_lds16(&Bw[(long)(n0 + row) * 1024 + kt + cb], &Bsm[c * 8]);
        }
        __syncthreads();
        f16x8 af[4], bf[4];
        #pragma unroll
        for (int m = 0; m < 4; ++m)
            af[m] = *(const f16x8*)&Asm[(wr * 64 + m * 16 + r16) * 32 + g * 8];
        #pragma unroll
        for (int n = 0; n < 4; ++n)
            bf[n] = *(const f16x8*)&Bsm[(wc * 64 + n * 16 + r16) * 32 + g * 8];
        #pragma unroll
        for (int m = 0; m < 4; ++m)
            #pragma unroll
            for (int n = 0; n < 4; ++n)
                acc[m][n] = __builtin_amdgcn_mfma_f32_16x16x32_f16(af[m], bf[n], acc[m][n], 0, 0, 0);
    }
}

// ---------- fused QKV projection; z=0->q, z=1->k (both [bh][t][d] f16), z=2->v^T [bh][d][t] ----------
__global__ __launch_bounds__(256)
void k_gemm_qkv(const _Float16* __restrict__ A,
                const _Float16* __restrict__ wq, const _Float16* __restrict__ wk,
                const _Float16* __restrict__ wv,
                const float* __restrict__ bq, const float* __restrict__ bk,
                const float* __restrict__ bv,
                const unsigned int* __restrict__ amax,
                _Float16* __restrict__ qo, _Float16* __restrict__ ko,
                _Float16* __restrict__ vto) {
    const int z = blockIdx.z;
    const _Float16* Bw = (z == 0) ? wq : (z == 1) ? wk : wv;
    const float* bias = (z == 0) ? bq : (z == 1) ? bk : bv;
    const int tid = threadIdx.x;
    const int m0 = blockIdx.y * 128, n0 = blockIdx.x * 128;
    const int lane = tid & 63, wid = tid >> 6;
    const int r16 = lane & 15, g = lane >> 4;
    const int wr = wid >> 1, wc = wid & 1;

    f32x4 acc[4][4];
    gemm_core(A, Bw, m0, n0, tid, acc);

    float sA = fmaxf(__uint_as_float(amax[0]) / 127.0f, 1e-8f);
    float sB = fmaxf(__uint_as_float(amax[1 + z]) / 127.0f, 1e-8f);
    float s = sA * sB;
    if (z < 2) {
        _Float16* out = (z == 0) ? qo : ko;
        #pragma unroll
        for (int m = 0; m < 4; ++m)
            #pragma unroll
            for (int n = 0; n < 4; ++n) {
                int col = n0 + wc * 64 + n * 16 + r16;
                float bcol = bias[col];
                int h = col >> 6, d = col & 63;
                #pragma unroll
                for (int r = 0; r < 4; ++r) {
                    int row = m0 + wr * 64 + m * 16 + g * 4 + r;
                    int b = row >> 11, t = row & 2047;
                    out[(((long)(b * NH + h)) * T_SEQ + t) * HD + d] =
                        (_Float16)(acc[m][n][r] * s + bcol);
                }
            }
    } else {
        #pragma unroll
        for (int m = 0; m < 4; ++m)
            #pragma unroll
            for (int n = 0; n < 4; ++n) {
                int col = n0 + wc * 64 + n * 16 + r16;
                float bcol = bias[col];
                int h = col >> 6, d = col & 63;
                int row0 = m0 + wr * 64 + m * 16 + g * 4;
                int b = row0 >> 11, t = row0 & 2047;
                f16x4 pk;
                #pragma unroll
                for (int r = 0; r < 4; ++r) pk[r] = (_Float16)(acc[m][n][r] * s + bcol);
                *(f16x4*)&vto[(((long)(b * NH + h)) * HD + d) * T_SEQ + t] = pk;
            }
    }
}

// ---------- output projection GEMM -> fp32 d_out ----------
__global__ __launch_bounds__(256)
void k_gemm_o(const _Float16* __restrict__ A, const _Float16* __restrict__ Bw,
              const float* __restrict__ bias,
              const unsigned int* __restrict__ amaxA, const unsigned int* __restrict__ amaxB,
              float* __restrict__ out) {
    const int tid = threadIdx.x;
    const int m0 = blockIdx.y * 128, n0 = blockIdx.x * 128;
    const int lane = tid & 63, wid = tid >> 6;
    const int r16 = lane & 15, g = lane >> 4;
    const int wr = wid >> 1, wc = wid & 1;

    f32x4 acc[4][4];
    gemm_core(A, Bw, m0, n0, tid, acc);

    float sA = fmaxf(__uint_as_float(*amaxA) / 127.0f, 1e-8f);
    float sB = fmaxf(__uint_as_float(*amaxB) / 127.0f, 1e-8f);
    float s = sA * sB;
    #pragma unroll
    for (int m = 0; m < 4; ++m)
        #pragma unroll
        for (int n = 0; n < 4; ++n) {
            int col = n0 + wc * 64 + n * 16 + r16;
            float bcol = bias[col];
            #pragma unroll
            for (int r = 0; r < 4; ++r) {
                int row = m0 + wr * 64 + m * 16 + g * 4 + r;
                out[(long)row * 1024 + col] = acc[m][n][r] * s + bcol;
            }
        }
}

// ---------- split-K flash attention: partials (o/l as f16, m, l) per (Q-tile, split) ----------
// grid x: 64 = (Jrev, z); J = 31 - (x>>1), z = x & 1.  LDS = 40960 B -> 4 blocks/CU.
__global__ __launch_bounds__(256)
void k_attn(const _Float16* __restrict__ q, const _Float16* __restrict__ kk,
            const _Float16* __restrict__ vt,
            _Float16* __restrict__ Op, float2* __restrict__ ML) {
    __shared__ _Float16 Kd[2][4096];       // [64][64] linear, chunk-XOR swizzled
    __shared__ _Float16 Vd[2][4096];
    __shared__ _Float16 Psm[4][1024];      // [16][64] per wave, chunk-XOR swizzled

    const int bh = blockIdx.y;
    const int J = 31 - (blockIdx.x >> 1);  // heavy Q-tiles dispatch first
    const int z = blockIdx.x & 1;
    const int t0 = J * 64;
    const int tid = threadIdx.x, wid = tid >> 6, lane = tid & 63;
    const int r16 = lane & 15, g = lane >> 4;
    const long base = (long)bh * T_SEQ * HD;
    const long vbase = (long)bh * HD * T_SEQ;

    const int nkt = J + 1;
    const int n0t = (nkt + 1) >> 1;
    const int tstart = z ? n0t : 0;
    const int tend = z ? nkt : n0t;
    const long prow = (long)(z * 32 + bh) * T_SEQ + t0;   // partial row base

    if (tend <= tstart) {                  // empty split: sentinel partials
        #pragma unroll
        for (int nb = 0; nb < 4; ++nb)
            #pragma unroll
            for (int r = 0; r < 4; ++r)
                Op[(prow + wid * 16 + g * 4 + r) * HD + nb * 16 + r16] = (_Float16)0.f;
        if (r16 == 0)
            #pragma unroll
            for (int r = 0; r < 4; ++r)
                ML[prow + wid * 16 + g * 4 + r] = make_float2(-INFINITY, 0.f);
        return;
    }

    auto STAGE = [&](int jt, int buf) {
        const _Float16* kp = kk + base + (long)jt * 64 * HD;
        const _Float16* vp = vt + vbase + jt * 64;
        #pragma unroll
        for (int s2 = 0; s2 < 2; ++s2) {
            int slot = tid + s2 * 256;           // linear LDS chunk (dest = base + lane*16)
            int row = slot >> 3;
            int ch = (slot & 7) ^ (row & 7);     // pre-swizzled global source chunk
            gload_lds16(kp + row * HD + ch * 8, &Kd[buf][slot * 8]);
            gload_lds16(vp + (long)row * T_SEQ + ch * 8, &Vd[buf][slot * 8]);
        }
    };

    f16x8 qf0, qf1;
    {
        const _Float16* qp = q + base + (long)(t0 + wid * 16 + r16) * HD + g * 8;
        qf0 = *(const f16x8*)qp;
        qf1 = *(const f16x8*)(qp + 32);
        #pragma unroll
        for (int u = 0; u < 8; ++u) { qf0[u] *= (_Float16)0.125f; qf1[u] *= (_Float16)0.125f; }
    }
    float mrun = -INFINITY;
    float lacc[4] = {0.f, 0.f, 0.f, 0.f};
    f32x4 oacc[4];
    #pragma unroll
    for (int nb = 0; nb < 4; ++nb) oacc[nb] = (f32x4){0.f, 0.f, 0.f, 0.f};

    STAGE(tstart, 0);
    int cur = 0;
    for (int jt = tstart; jt < tend; ++jt) {
        __syncthreads();                     // drains vmcnt: buf[cur] ready
        if (jt + 1 < tend) STAGE(jt + 1, cur ^ 1);   // prefetch under compute

        const _Float16* Kc = &Kd[cur][0];
        const _Float16* Vc = &Vd[cur][0];
        f32x4 s[4];
        #pragma unroll
        for (int nb = 0; nb < 4; ++nb) {
            int row = nb * 16 + r16;
            f16x8 kb0 = *(const f16x8*)&Kc[row * 64 + (((g)     ^ (row & 7)) << 3)];
            f16x8 kb1 = *(const f16x8*)&Kc[row * 64 + (((4 + g) ^ (row & 7)) << 3)];
            f32x4 a = (f32x4){0.f, 0.f, 0.f, 0.f};
            a = __builtin_amdgcn_mfma_f32_16x16x32_f16(qf0, kb0, a, 0, 0, 0);
            a = __builtin_amdgcn_mfma_f32_16x16x32_f16(qf1, kb1, a, 0, 0, 0);
            s[nb] = a;
        }
        if (jt == J) {                       // diagonal: causal mask
            #pragma unroll
            for (int nb = 0; nb < 4; ++nb)
                #pragma unroll
                for (int r = 0; r < 4; ++r)
                    if (nb * 16 + r16 > wid * 16 + g * 4 + r) s[nb][r] = -INFINITY;
        }
        // wave-uniform tile max + deferred rescale (THR=8; p <= e^8 fits f16)
        float M = s[0][0];
        #pragma unroll
        for (int nb = 0; nb < 4; ++nb)
            #pragma unroll
            for (int r = 0; r < 4; ++r) M = fmaxf(M, s[nb][r]);
        #pragma unroll
        for (int off = 1; off < 64; off <<= 1) M = fmaxf(M, __shfl_xor(M, off));
        if (M > mrun + 8.f) {
            float corr = __expf(mrun - M);   // first tile: exp(-inf)=0
            #pragma unroll
            for (int r = 0; r < 4; ++r) lacc[r] *= corr;
            #pragma unroll
            for (int nb = 0; nb < 4; ++nb)
                #pragma unroll
                for (int r = 0; r < 4; ++r) oacc[nb][r] *= corr;
            mrun = M;
        }
        #pragma unroll
        for (int nb = 0; nb < 4; ++nb)
            #pragma unroll
            for (int r = 0; r < 4; ++r) {
                float p = __expf(s[nb][r] - mrun);
                lacc[r] += p;                // per-lane deferred l; reduced once at end
                int row = g * 4 + r, col = nb * 16 + r16;
                int c8 = col >> 3;
                Psm[wid][row * 64 + ((c8 ^ (row & 7)) << 3) + (col & 7)] = (_Float16)p;
            }
        f16x8 pa0 = *(const f16x8*)&Psm[wid][r16 * 64 + (((g)     ^ (r16 & 7)) << 3)];
        f16x8 pa1 = *(const f16x8*)&Psm[wid][r16 * 64 + (((4 + g) ^ (r16 & 7)) << 3)];
        #pragma unroll
        for (int nb = 0; nb < 4; ++nb) {
            int row = nb * 16 + r16;
            f16x8 vb0 = *(const f16x8*)&Vc[row * 64 + (((g)     ^ (row & 7)) << 3)];
            f16x8 vb1 = *(const f16x8*)&Vc[row * 64 + (((4 + g) ^ (row & 7)) << 3)];
            oacc[nb] = __builtin_amdgcn_mfma_f32_16x16x32_f16(pa0, vb0, oacc[nb], 0, 0, 0);
            oacc[nb] = __builtin_amdgcn_mfma_f32_16x16x32_f16(pa1, vb1, oacc[nb], 0, 0, 0);
        }
        cur ^= 1;
    }
    // epilogue: reduce row sums, write normalized partials + (m, l)
    float lsum[4];
    #pragma unroll
    for (int r = 0; r < 4; ++r) {
        float L = lacc[r];
        #pragma unroll
        for (int off = 1; off < 16; off <<= 1) L += __shfl_xor(L, off);
        lsum[r] = L;
    }
    #pragma unroll
    for (int nb = 0; nb < 4; ++nb)
        #pragma unroll
        for (int r = 0; r < 4; ++r)
            Op[(prow + wid * 16 + g * 4 + r) * HD + nb * 16 + r16] =
                (_Float16)(oacc[nb][r] / lsum[r]);
    if (r16 == 0)
        #pragma unroll
        for (int r = 0; r < 4; ++r)
            ML[prow + wid * 16 + g * 4 + r] = make_float2(mrun, lsum[r]);
}

// ---------- combine split-K partials -> y fp32; folds absmax(y) ----------
__global__ __launch_bounds__(256)
void k_combine(const _Float16* __restrict__ Op, const float2* __restrict__ ML,
               float* __restrict__ y, unsigned int* __restrict__ amax5) {
    __shared__ float wmax[4];
    const int tid = threadIdx.x;
    const int d = tid & 63, wr = tid >> 6;
    float bmax = 0.f;
    #pragma unroll 1
    for (int it = 0; it < 16; ++it) {
        int row = (blockIdx.x * 16 + it) * 4 + wr;       // 0..65535 = bh*2048 + t
        float2 ml0 = ML[row];
        float2 ml1 = ML[65536 + row];
        float M = fmaxf(ml0.x, ml1.x);
        float w0 = __expf(ml0.x - M) * ml0.y;
        float w1 = __expf(ml1.x - M) * ml1.y;
        float o0 = (float)Op[(long)row * HD + d];
        float o1 = (float)Op[(long)(65536 + row) * HD + d];
        float val = (w0 * o0 + w1 * o1) / (w0 + w1);
        int bh = row >> 11, t = row & 2047;
        y[((long)((bh >> 4) * T_SEQ + t)) * D_MODEL + (bh & 15) * HD + d] = val;
        bmax = fmaxf(bmax, fabsf(val));
    }
    #pragma unroll
    for (int off = 1; off < 64; off <<= 1) bmax = fmaxf(bmax, __shfl_xor(bmax, off));
    if ((tid & 63) == 0) wmax[wr] = bmax;
    __syncthreads();
    if (tid == 0) {
        float m = fmaxf(fmaxf(wmax[0], wmax[1]), fmaxf(wmax[2], wmax[3]));
        if (m > 0.f) atomicMax(amax5, __float_as_uint(m));
    }
}

// ---------------- launch ----------------
extern "C" void kernel_launch(void* const* d_in, const int* in_sizes, int n_in,
                              void* d_out, int out_size, void* d_ws, size_t ws_size,
                              hipStream_t stream) {
    const float* x  = (const float*)d_in[0];
    const float* Wq = (const float*)d_in[1];
    const float* bq = (const float*)d_in[2];
    const float* Wk = (const float*)d_in[3];
    const float* bk = (const float*)d_in[4];
    const float* Wv = (const float*)d_in[5];
    const float* bv = (const float*)d_in[6];
    const float* Wo = (const float*)d_in[7];
    const float* bo = (const float*)d_in[8];

    char* ws = (char*)d_ws;
    unsigned int* amax = (unsigned int*)ws;                     // 256 B
    _Float16* xq  = (_Float16*)(ws + 256);                      // 8 MB
    _Float16* wqh = (_Float16*)(ws + 256 + 8388608L);           // 2 MB each
    _Float16* wkh = (_Float16*)(ws + 256 + 8388608L + 2097152L);
    _Float16* wvh = (_Float16*)(ws + 256 + 8388608L + 2L * 2097152L);
    _Float16* woh = (_Float16*)(ws + 256 + 8388608L + 3L * 2097152L);
    char* p2 = ws + 256 + 8388608L + 4L * 2097152L;
    _Float16* qh  = (_Float16*)p2;                              // 8 MB each
    _Float16* kh  = (_Float16*)(p2 + 8388608L);
    _Float16* vth = (_Float16*)(p2 + 2L * 8388608L);
    float*    yb  = (float*)(p2 + 3L * 8388608L);               // 16 MB fp32
    _Float16* yq  = (_Float16*)(p2 + 3L * 8388608L + 16777216L);// 8 MB
    _Float16* Opart = (_Float16*)(p2 + 3L * 8388608L + 16777216L + 8388608L);  // 16 MB
    float2*   MLp   = (float2*)(p2 + 3L * 8388608L + 16777216L + 8388608L + 16777216L); // 1 MB

    const long NX4 = (long)NB * T_SEQ * D_MODEL / 4;            // 1048576

    hipMemsetAsync(amax, 0, 256, stream);
    k_absmax8<<<dim3(128, 8), 256, 0, stream>>>(x, Wq, Wk, Wv, Wo, amax);
    k_quant8<<<dim3(128, 8), 256, 0, stream>>>(x, Wq, Wk, Wv, Wo,
                                               xq, wqh, wkh, wvh, woh, amax);
    k_gemm_qkv<<<dim3(8, 32, 3), 256, 0, stream>>>(xq, wqh, wkh, wvh, bq, bk, bv,
                                                   amax, qh, kh, vth);
    k_attn<<<dim3(64, 32), 256, 0, stream>>>(qh, kh, vth, Opart, MLp);
    k_combine<<<1024, 256, 0, stream>>>(Opart, MLp, yb, amax + 5);
    k_quant<<<1024, 256, 0, stream>>>(yb, yq, amax + 5, NX4);
    k_gemm_o<<<dim3(8, 32), 256, 0, stream>>>(yq, woh, bo, amax + 5, amax + 4, (float*)d_out);
}

// Round 6
// 220.176 us; speedup vs baseline: 1.0733x; 1.0733x over previous
//
#include <hip/hip_runtime.h>
#include <hip/hip_fp16.h>

#define T_SEQ 2048
#define D_MODEL 1024
#define NB 2
#define NH 16
#define HD 64

using f16x8 = __attribute__((ext_vector_type(8))) _Float16;
using f16x4 = __attribute__((ext_vector_type(4))) _Float16;
using f32x4 = __attribute__((ext_vector_type(4))) float;

__device__ __forceinline__ float fexp2(float x) { return __builtin_amdgcn_exp2f(x); }

__device__ __forceinline__ void gload_lds16(const void* g, void* l) {
    __builtin_amdgcn_global_load_lds((const __attribute__((address_space(1))) void*)g,
                                     (__attribute__((address_space(3))) void*)l, 16, 0, 0);
}

// ---------- absmax: y<4 -> x slice y (slot 0); y>=4 -> W[y-4] (slot 1+y-4) ----------
__global__ __launch_bounds__(256)
void k_absmax8(const float* __restrict__ x,
               const float* __restrict__ w0, const float* __restrict__ w1,
               const float* __restrict__ w2, const float* __restrict__ w3,
               unsigned int* __restrict__ amax) {
    const int y = blockIdx.y;
    const float* p; int slot;
    if (y < 4) { p = x + (long)y * 1048576; slot = 0; }
    else { int w = y - 4; p = (w == 0) ? w0 : (w == 1) ? w1 : (w == 2) ? w2 : w3; slot = 1 + w; }
    const long n4 = 262144;
    long i = (long)blockIdx.x * blockDim.x + threadIdx.x;
    const long stride = (long)gridDim.x * blockDim.x;
    float m = 0.f;
    for (; i < n4; i += stride) {
        float4 v = ((const float4*)p)[i];
        m = fmaxf(fmaxf(fmaxf(fabsf(v.x), fabsf(v.y)), fmaxf(fabsf(v.z), fabsf(v.w))), m);
    }
    #pragma unroll
    for (int off = 32; off; off >>= 1) m = fmaxf(m, __shfl_xor(m, off));
    if ((threadIdx.x & 63) == 0 && m > 0.f) atomicMax(amax + slot, __float_as_uint(m));
}

// ---------- quantize to integer codes (f16): same y decode as k_absmax8 ----------
__global__ __launch_bounds__(256)
void k_quant8(const float* __restrict__ x,
              const float* __restrict__ w0, const float* __restrict__ w1,
              const float* __restrict__ w2, const float* __restrict__ w3,
              _Float16* __restrict__ xq,
              _Float16* __restrict__ o0, _Float16* __restrict__ o1,
              _Float16* __restrict__ o2, _Float16* __restrict__ o3,
              const unsigned int* __restrict__ amax) {
    const int y = blockIdx.y;
    const float* p; _Float16* o; int slot;
    if (y < 4) { p = x + (long)y * 1048576; o = xq + (long)y * 1048576; slot = 0; }
    else {
        int w = y - 4;
        p = (w == 0) ? w0 : (w == 1) ? w1 : (w == 2) ? w2 : w3;
        o = (w == 0) ? o0 : (w == 1) ? o1 : (w == 2) ? o2 : o3;
        slot = 1 + w;
    }
    float scale = fmaxf(__uint_as_float(amax[slot]) / 127.0f, 1e-8f);
    const long n4 = 262144;
    long i = (long)blockIdx.x * blockDim.x + threadIdx.x;
    const long stride = (long)gridDim.x * blockDim.x;
    for (; i < n4; i += stride) {
        float4 v = ((const float4*)p)[i];
        f16x4 q;
        q[0] = (_Float16)fminf(127.f, fmaxf(-128.f, rintf(v.x / scale)));
        q[1] = (_Float16)fminf(127.f, fmaxf(-128.f, rintf(v.y / scale)));
        q[2] = (_Float16)fminf(127.f, fmaxf(-128.f, rintf(v.z / scale)));
        q[3] = (_Float16)fminf(127.f, fmaxf(-128.f, rintf(v.w / scale)));
        ((f16x4*)o)[i] = q;
    }
}

// plain quant for y buffer
__global__ __launch_bounds__(256)
void k_quant(const float* __restrict__ in, _Float16* __restrict__ out,
             const unsigned int* __restrict__ amax, long n4) {
    float scale = fmaxf(__uint_as_float(*amax) / 127.0f, 1e-8f);
    long i = (long)blockIdx.x * blockDim.x + threadIdx.x;
    const long stride = (long)gridDim.x * blockDim.x;
    for (; i < n4; i += stride) {
        float4 v = ((const float4*)in)[i];
        f16x4 q;
        q[0] = (_Float16)fminf(127.f, fmaxf(-128.f, rintf(v.x / scale)));
        q[1] = (_Float16)fminf(127.f, fmaxf(-128.f, rintf(v.y / scale)));
        q[2] = (_Float16)fminf(127.f, fmaxf(-128.f, rintf(v.z / scale)));
        q[3] = (_Float16)fminf(127.f, fmaxf(-128.f, rintf(v.w / scale)));
        ((f16x4*)out)[i] = q;
    }
}

// ---------- shared GEMM core: 128x128 tile, K=1024, codes @ codes^T ----------
__device__ __forceinline__ void gemm_core(const _Float16* __restrict__ A,
                                          const _Float16* __restrict__ Bw,
                                          int m0, int n0, int tid, f32x4 (&acc)[4][4]) {
    __shared__ _Float16 Asm[128 * 32];
    __shared__ _Float16 Bsm[128 * 32];
    const int lane = tid & 63, wid = tid >> 6;
    const int r16 = lane & 15, g = lane >> 4;
    const int wr = wid >> 1, wc = wid & 1;
    #pragma unroll
    for (int m = 0; m < 4; ++m)
        #pragma unroll
        for (int n = 0; n < 4; ++n) acc[m][n] = (f32x4){0.f, 0.f, 0.f, 0.f};
    for (int kt = 0; kt < 1024; kt += 32) {
        __syncthreads();
        #pragma unroll
        for (int s2 = 0; s2 < 2; ++s2) {
            int c = tid + s2 * 256;
            int row = c >> 2, cb = (c & 3) * 8;
            gload_lds16(&A[(long)(m0 + row) * 1024 + kt + cb], &Asm[c * 8]);
            gload_lds16(&Bw[(long)(n0 + row) * 1024 + kt + cb], &Bsm[c * 8]);
        }
        __syncthreads();
        f16x8 af[4], bf[4];
        #pragma unroll
        for (int m = 0; m < 4; ++m)
            af[m] = *(const f16x8*)&Asm[(wr * 64 + m * 16 + r16) * 32 + g * 8];
        #pragma unroll
        for (int n = 0; n < 4; ++n)
            bf[n] = *(const f16x8*)&Bsm[(wc * 64 + n * 16 + r16) * 32 + g * 8];
        #pragma unroll
        for (int m = 0; m < 4; ++m)
            #pragma unroll
            for (int n = 0; n < 4; ++n)
                acc[m][n] = __builtin_amdgcn_mfma_f32_16x16x32_f16(af[m], bf[n], acc[m][n], 0, 0, 0);
    }
}

// ---------- fused QKV projection; z=0->q, z=1->k (both [bh][t][d] f16), z=2->v^T [bh][d][t] ----------
__global__ __launch_bounds__(256)
void k_gemm_qkv(const _Float16* __restrict__ A,
                const _Float16* __restrict__ wq, const _Float16* __restrict__ wk,
                const _Float16* __restrict__ wv,
                const float* __restrict__ bq, const float* __restrict__ bk,
                const float* __restrict__ bv,
                const unsigned int* __restrict__ amax,
                _Float16* __restrict__ qo, _Float16* __restrict__ ko,
                _Float16* __restrict__ vto) {
    const int z = blockIdx.z;
    const _Float16* Bw = (z == 0) ? wq : (z == 1) ? wk : wv;
    const float* bias = (z == 0) ? bq : (z == 1) ? bk : bv;
    const int tid = threadIdx.x;
    const int m0 = blockIdx.y * 128, n0 = blockIdx.x * 128;
    const int lane = tid & 63, wid = tid >> 6;
    const int r16 = lane & 15, g = lane >> 4;
    const int wr = wid >> 1, wc = wid & 1;

    f32x4 acc[4][4];
    gemm_core(A, Bw, m0, n0, tid, acc);

    float sA = fmaxf(__uint_as_float(amax[0]) / 127.0f, 1e-8f);
    float sB = fmaxf(__uint_as_float(amax[1 + z]) / 127.0f, 1e-8f);
    float s = sA * sB;
    if (z < 2) {
        _Float16* out = (z == 0) ? qo : ko;
        #pragma unroll
        for (int m = 0; m < 4; ++m)
            #pragma unroll
            for (int n = 0; n < 4; ++n) {
                int col = n0 + wc * 64 + n * 16 + r16;
                float bcol = bias[col];
                int h = col >> 6, d = col & 63;
                #pragma unroll
                for (int r = 0; r < 4; ++r) {
                    int row = m0 + wr * 64 + m * 16 + g * 4 + r;
                    int b = row >> 11, t = row & 2047;
                    out[(((long)(b * NH + h)) * T_SEQ + t) * HD + d] =
                        (_Float16)(acc[m][n][r] * s + bcol);
                }
            }
    } else {
        #pragma unroll
        for (int m = 0; m < 4; ++m)
            #pragma unroll
            for (int n = 0; n < 4; ++n) {
                int col = n0 + wc * 64 + n * 16 + r16;
                float bcol = bias[col];
                int h = col >> 6, d = col & 63;
                int row0 = m0 + wr * 64 + m * 16 + g * 4;
                int b = row0 >> 11, t = row0 & 2047;
                f16x4 pk;
                #pragma unroll
                for (int r = 0; r < 4; ++r) pk[r] = (_Float16)(acc[m][n][r] * s + bcol);
                *(f16x4*)&vto[(((long)(b * NH + h)) * HD + d) * T_SEQ + t] = pk;
            }
    }
}

// ---------- output projection GEMM, 128x64 tiles (512 blocks, 2/CU) -> fp32 d_out ----------
__global__ __launch_bounds__(256)
void k_gemm_o(const _Float16* __restrict__ A, const _Float16* __restrict__ Bw,
              const float* __restrict__ bias,
              const unsigned int* __restrict__ amaxA, const unsigned int* __restrict__ amaxB,
              float* __restrict__ out) {
    __shared__ _Float16 Asm[128 * 32];
    __shared__ _Float16 Bsm[64 * 32];
    const int tid = threadIdx.x;
    const int m0 = blockIdx.y * 128, n0 = blockIdx.x * 64;
    const int lane = tid & 63, wid = tid >> 6;
    const int r16 = lane & 15, g = lane >> 4;
    const int wr = wid >> 1, wc = wid & 1;

    f32x4 acc[4][2];
    #pragma unroll
    for (int m = 0; m < 4; ++m)
        #pragma unroll
        for (int n = 0; n < 2; ++n) acc[m][n] = (f32x4){0.f, 0.f, 0.f, 0.f};

    for (int kt = 0; kt < 1024; kt += 32) {
        __syncthreads();
        #pragma unroll
        for (int s2 = 0; s2 < 2; ++s2) {
            int c = tid + s2 * 256;
            int row = c >> 2, cb = (c & 3) * 8;
            gload_lds16(&A[(long)(m0 + row) * 1024 + kt + cb], &Asm[c * 8]);
        }
        {
            int row = tid >> 2, cb = (tid & 3) * 8;
            gload_lds16(&Bw[(long)(n0 + row) * 1024 + kt + cb], &Bsm[tid * 8]);
        }
        __syncthreads();
        f16x8 af[4], bf[2];
        #pragma unroll
        for (int m = 0; m < 4; ++m)
            af[m] = *(const f16x8*)&Asm[(wr * 64 + m * 16 + r16) * 32 + g * 8];
        #pragma unroll
        for (int n = 0; n < 2; ++n)
            bf[n] = *(const f16x8*)&Bsm[(wc * 32 + n * 16 + r16) * 32 + g * 8];
        #pragma unroll
        for (int m = 0; m < 4; ++m)
            #pragma unroll
            for (int n = 0; n < 2; ++n)
                acc[m][n] = __builtin_amdgcn_mfma_f32_16x16x32_f16(af[m], bf[n], acc[m][n], 0, 0, 0);
    }

    float sA = fmaxf(__uint_as_float(*amaxA) / 127.0f, 1e-8f);
    float sB = fmaxf(__uint_as_float(*amaxB) / 127.0f, 1e-8f);
    float s = sA * sB;
    #pragma unroll
    for (int m = 0; m < 4; ++m)
        #pragma unroll
        for (int n = 0; n < 2; ++n) {
            int col = n0 + wc * 32 + n * 16 + r16;
            float bcol = bias[col];
            #pragma unroll
            for (int r = 0; r < 4; ++r) {
                int row = m0 + wr * 64 + m * 16 + g * 4 + r;
                out[(long)row * 1024 + col] = acc[m][n][r] * s + bcol;
            }
        }
}

// ---------- flash attention: paired Q-tiles + even split-K -> uniform 16/17 steps/block ----------
// grid (32, 32): x = p*2+z, pair (Jh=31-p, Jl=p); 1024 blocks = exactly 4/CU (LDS 40960).
// Scores in log2 domain (log2e folded into Q scale); partials: Op f16 normalized, ML=(m_log2, l).
__global__ __launch_bounds__(256)
void k_attn(const _Float16* __restrict__ q, const _Float16* __restrict__ kk,
            const _Float16* __restrict__ vt,
            _Float16* __restrict__ Op, float2* __restrict__ ML) {
    __shared__ _Float16 Kd[2][4096];       // [64][64] linear, chunk-XOR swizzled
    __shared__ _Float16 Vd[2][4096];
    __shared__ _Float16 Psm[4][1024];      // [16][64] per wave, chunk-XOR swizzled

    const int bh = blockIdx.y;
    const int p = blockIdx.x >> 1, z = blockIdx.x & 1;
    const int tid = threadIdx.x, wid = tid >> 6, lane = tid & 63;
    const int r16 = lane & 15, g = lane >> 4;
    const long base = (long)bh * T_SEQ * HD;
    const long vbase = (long)bh * HD * T_SEQ;

    auto STAGE = [&](int jt, int buf) {
        const _Float16* kp = kk + base + (long)jt * 64 * HD;
        const _Float16* vp = vt + vbase + jt * 64;
        #pragma unroll
        for (int s2 = 0; s2 < 2; ++s2) {
            int slot = tid + s2 * 256;           // linear LDS chunk (dest = base + lane*16)
            int row = slot >> 3;
            int ch = (slot & 7) ^ (row & 7);     // pre-swizzled global source chunk
            gload_lds16(kp + row * HD + ch * 8, &Kd[buf][slot * 8]);
            gload_lds16(vp + (long)row * T_SEQ + ch * 8, &Vd[buf][slot * 8]);
        }
    };

    #pragma unroll 1
    for (int sub = 0; sub < 2; ++sub) {
        const int J = sub ? p : (31 - p);
        const int nk = J + 1;
        const int c = sub ? (nk >> 1) : ((nk + 1) >> 1);   // Jh: ceil to z0; Jl: floor to z0
        const int a = z ? c : 0;
        const int b = z ? nk : c;
        const int t0 = J * 64;
        const long prow = (long)(z * 32 + bh) * T_SEQ + t0;

        if (a >= b) {                          // only (p=0, z=0, Jl): sentinel partials
            #pragma unroll
            for (int nb = 0; nb < 4; ++nb)
                #pragma unroll
                for (int r = 0; r < 4; ++r)
                    Op[(prow + wid * 16 + g * 4 + r) * HD + nb * 16 + r16] = (_Float16)0.f;
            if (r16 == 0)
                #pragma unroll
                for (int r = 0; r < 4; ++r)
                    ML[prow + wid * 16 + g * 4 + r] = make_float2(-INFINITY, 0.f);
            continue;
        }

        f16x8 qf0, qf1;
        {
            const _Float16* qp = q + base + (long)(t0 + wid * 16 + r16) * HD + g * 8;
            qf0 = *(const f16x8*)qp;
            qf1 = *(const f16x8*)(qp + 32);
            #pragma unroll
            for (int u = 0; u < 8; ++u) {      // fold 1/sqrt(64) * log2(e): scores in log2 domain
                qf0[u] *= (_Float16)0.18033688f;
                qf1[u] *= (_Float16)0.18033688f;
            }
        }
        float mrun = -INFINITY;
        float lacc[4] = {0.f, 0.f, 0.f, 0.f};
        f32x4 oacc[4];
        #pragma unroll
        for (int nb = 0; nb < 4; ++nb) oacc[nb] = (f32x4){0.f, 0.f, 0.f, 0.f};

        __syncthreads();                       // prev sub's buffers fully consumed
        STAGE(a, 0);
        int cur = 0;
        for (int jt = a; jt < b; ++jt) {
            __syncthreads();                   // drains vmcnt: buf[cur] ready
            if (jt + 1 < b) STAGE(jt + 1, cur ^ 1);   // prefetch under compute

            const _Float16* Kc = &Kd[cur][0];
            const _Float16* Vc = &Vd[cur][0];
            f32x4 s[4];
            __builtin_amdgcn_s_setprio(1);
            #pragma unroll
            for (int nb = 0; nb < 4; ++nb) {
                int row = nb * 16 + r16;
                f16x8 kb0 = *(const f16x8*)&Kc[row * 64 + (((g)     ^ (row & 7)) << 3)];
                f16x8 kb1 = *(const f16x8*)&Kc[row * 64 + (((4 + g) ^ (row & 7)) << 3)];
                f32x4 acc0 = (f32x4){0.f, 0.f, 0.f, 0.f};
                acc0 = __builtin_amdgcn_mfma_f32_16x16x32_f16(qf0, kb0, acc0, 0, 0, 0);
                acc0 = __builtin_amdgcn_mfma_f32_16x16x32_f16(qf1, kb1, acc0, 0, 0, 0);
                s[nb] = acc0;
            }
            __builtin_amdgcn_s_setprio(0);
            if (jt == J) {                     // diagonal: causal mask
                #pragma unroll
                for (int nb = 0; nb < 4; ++nb)
                    #pragma unroll
                    for (int r = 0; r < 4; ++r)
                        if (nb * 16 + r16 > wid * 16 + g * 4 + r) s[nb][r] = -INFINITY;
            }
            // per-lane max; full reduce+rescale only when any lane exceeds defer threshold
            float Ml = s[0][0];
            #pragma unroll
            for (int nb = 0; nb < 4; ++nb)
                #pragma unroll
                for (int r = 0; r < 4; ++r) Ml = fmaxf(Ml, s[nb][r]);
            if (__any(Ml > mrun + 11.5f)) {    // 11.5 = 8 * log2(e): p <= e^8 fits f16
                float M = Ml;
                #pragma unroll
                for (int off = 1; off < 64; off <<= 1) M = fmaxf(M, __shfl_xor(M, off));
                float corr = fexp2(mrun - M);
                #pragma unroll
                for (int r = 0; r < 4; ++r) lacc[r] *= corr;
                #pragma unroll
                for (int nb = 0; nb < 4; ++nb)
                    #pragma unroll
                    for (int r = 0; r < 4; ++r) oacc[nb][r] *= corr;
                mrun = M;
            }
            #pragma unroll
            for (int nb = 0; nb < 4; ++nb)
                #pragma unroll
                for (int r = 0; r < 4; ++r) {
                    float pv = fexp2(s[nb][r] - mrun);
                    lacc[r] += pv;             // per-lane deferred l; reduced once at end
                    int row = g * 4 + r, col = nb * 16 + r16;
                    int c8 = col >> 3;
                    Psm[wid][row * 64 + ((c8 ^ (row & 7)) << 3) + (col & 7)] = (_Float16)pv;
                }
            f16x8 pa0 = *(const f16x8*)&Psm[wid][r16 * 64 + (((g)     ^ (r16 & 7)) << 3)];
            f16x8 pa1 = *(const f16x8*)&Psm[wid][r16 * 64 + (((4 + g) ^ (r16 & 7)) << 3)];
            __builtin_amdgcn_s_setprio(1);
            #pragma unroll
            for (int nb = 0; nb < 4; ++nb) {
                int row = nb * 16 + r16;
                f16x8 vb0 = *(const f16x8*)&Vc[row * 64 + (((g)     ^ (row & 7)) << 3)];
                f16x8 vb1 = *(const f16x8*)&Vc[row * 64 + (((4 + g) ^ (row & 7)) << 3)];
                oacc[nb] = __builtin_amdgcn_mfma_f32_16x16x32_f16(pa0, vb0, oacc[nb], 0, 0, 0);
                oacc[nb] = __builtin_amdgcn_mfma_f32_16x16x32_f16(pa1, vb1, oacc[nb], 0, 0, 0);
            }
            __builtin_amdgcn_s_setprio(0);
            cur ^= 1;
        }
        // epilogue: reduce row sums, write normalized partials + (m_log2, l)
        float lsum[4];
        #pragma unroll
        for (int r = 0; r < 4; ++r) {
            float L = lacc[r];
            #pragma unroll
            for (int off = 1; off < 16; off <<= 1) L += __shfl_xor(L, off);
            lsum[r] = L;
        }
        #pragma unroll
        for (int nb = 0; nb < 4; ++nb)
            #pragma unroll
            for (int r = 0; r < 4; ++r)
                Op[(prow + wid * 16 + g * 4 + r) * HD + nb * 16 + r16] =
                    (_Float16)(oacc[nb][r] / lsum[r]);
        if (r16 == 0)
            #pragma unroll
            for (int r = 0; r < 4; ++r)
                ML[prow + wid * 16 + g * 4 + r] = make_float2(mrun, lsum[r]);
    }
}

// ---------- combine split-K partials -> y fp32; folds absmax(y).  m is log2-domain. ----------
__global__ __launch_bounds__(256)
void k_combine(const _Float16* __restrict__ Op, const float2* __restrict__ ML,
               float* __restrict__ y, unsigned int* __restrict__ amax5) {
    __shared__ float wmax[4];
    const int tid = threadIdx.x;
    const int d = tid & 63, wr = tid >> 6;
    float bmax = 0.f;
    #pragma unroll 1
    for (int it = 0; it < 16; ++it) {
        int row = (blockIdx.x * 16 + it) * 4 + wr;       // 0..65535 = bh*2048 + t
        float2 ml0 = ML[row];
        float2 ml1 = ML[65536 + row];
        float M = fmaxf(ml0.x, ml1.x);
        float w0 = fexp2(ml0.x - M) * ml0.y;
        float w1 = fexp2(ml1.x - M) * ml1.y;
        float o0 = (float)Op[(long)row * HD + d];
        float o1 = (float)Op[(long)(65536 + row) * HD + d];
        float val = (w0 * o0 + w1 * o1) / (w0 + w1);
        int bh = row >> 11, t = row & 2047;
        y[((long)((bh >> 4) * T_SEQ + t)) * D_MODEL + (bh & 15) * HD + d] = val;
        bmax = fmaxf(bmax, fabsf(val));
    }
    #pragma unroll
    for (int off = 1; off < 64; off <<= 1) bmax = fmaxf(bmax, __shfl_xor(bmax, off));
    if ((tid & 63) == 0) wmax[wr] = bmax;
    __syncthreads();
    if (tid == 0) {
        float m = fmaxf(fmaxf(wmax[0], wmax[1]), fmaxf(wmax[2], wmax[3]));
        if (m > 0.f) atomicMax(amax5, __float_as_uint(m));
    }
}

// ---------------- launch ----------------
extern "C" void kernel_launch(void* const* d_in, const int* in_sizes, int n_in,
                              void* d_out, int out_size, void* d_ws, size_t ws_size,
                              hipStream_t stream) {
    const float* x  = (const float*)d_in[0];
    const float* Wq = (const float*)d_in[1];
    const float* bq = (const float*)d_in[2];
    const float* Wk = (const float*)d_in[3];
    const float* bk = (const float*)d_in[4];
    const float* Wv = (const float*)d_in[5];
    const float* bv = (const float*)d_in[6];
    const float* Wo = (const float*)d_in[7];
    const float* bo = (const float*)d_in[8];

    char* ws = (char*)d_ws;
    unsigned int* amax = (unsigned int*)ws;                     // 256 B
    _Float16* xq  = (_Float16*)(ws + 256);                      // 8 MB
    _Float16* wqh = (_Float16*)(ws + 256 + 8388608L);           // 2 MB each
    _Float16* wkh = (_Float16*)(ws + 256 + 8388608L + 2097152L);
    _Float16* wvh = (_Float16*)(ws + 256 + 8388608L + 2L * 2097152L);
    _Float16* woh = (_Float16*)(ws + 256 + 8388608L + 3L * 2097152L);
    char* p2 = ws + 256 + 8388608L + 4L * 2097152L;
    _Float16* qh  = (_Float16*)p2;                              // 8 MB each
    _Float16* kh  = (_Float16*)(p2 + 8388608L);
    _Float16* vth = (_Float16*)(p2 + 2L * 8388608L);
    float*    yb  = (float*)(p2 + 3L * 8388608L);               // 16 MB fp32
    _Float16* yq  = (_Float16*)(p2 + 3L * 8388608L + 16777216L);// 8 MB
    _Float16* Opart = (_Float16*)(p2 + 3L * 8388608L + 16777216L + 8388608L);  // 16 MB
    float2*   MLp   = (float2*)(p2 + 3L * 8388608L + 16777216L + 8388608L + 16777216L); // 1 MB

    const long NX4 = (long)NB * T_SEQ * D_MODEL / 4;            // 1048576

    (void)hipMemsetAsync(amax, 0, 256, stream);
    k_absmax8<<<dim3(128, 8), 256, 0, stream>>>(x, Wq, Wk, Wv, Wo, amax);
    k_quant8<<<dim3(128, 8), 256, 0, stream>>>(x, Wq, Wk, Wv, Wo,
                                               xq, wqh, wkh, wvh, woh, amax);
    k_gemm_qkv<<<dim3(8, 32, 3), 256, 0, stream>>>(xq, wqh, wkh, wvh, bq, bk, bv,
                                                   amax, qh, kh, vth);
    k_attn<<<dim3(32, 32), 256, 0, stream>>>(qh, kh, vth, Opart, MLp);
    k_combine<<<1024, 256, 0, stream>>>(Opart, MLp, yb, amax + 5);
    k_quant<<<1024, 256, 0, stream>>>(yb, yq, amax + 5, NX4);
    k_gemm_o<<<dim3(16, 32), 256, 0, stream>>>(yq, woh, bo, amax + 5, amax + 4, (float*)d_out);
}